// Round 4
// baseline (586.276 us; speedup 1.0000x reference)
//
#include <hip/hip_runtime.h>

typedef __attribute__((ext_vector_type(8))) short bf16x8;
typedef __attribute__((ext_vector_type(4))) float f32x4;

#define WS_QKV   0          // 384 KiB: qkv frags (48 rt * 8 ks * 1024B), q-rows prescaled
#define WS_PROJ  393216     // 128 KiB: proj frags (16 rt * 8 ks * 1024B)
#define WS_MASKP 524288     // 1 MiB: maskp[64][64][64] f32 * log2e (j>=49 -> -1e30)
#define WS_BIAS  1572864    // 128 KiB: bias_hm[8][64][64] f32 * log2e
#define WS_QB    1703936    // 3 KiB: qkvb_s[768] (q part prescaled by scale*log2e)

#define QSCALE 0.17677669529663687f   // 1/sqrt(32)
#define LOG2E  1.4426950408889634f

__device__ __forceinline__ unsigned short f2bf(float f) {
  unsigned u = __builtin_bit_cast(unsigned, f);
  u += 0x7FFFu + ((u >> 16) & 1u);
  return (unsigned short)(u >> 16);
}

__device__ __forceinline__ unsigned long long pack4bf(f32x4 v) {
  unsigned long long r0 = f2bf(v[0]);
  unsigned long long r1 = f2bf(v[1]);
  unsigned long long r2 = f2bf(v[2]);
  unsigned long long r3 = f2bf(v[3]);
  return r0 | (r1 << 16) | (r2 << 32) | (r3 << 48);
}

// frag(rt,ks): lane l holds W[16*rt + (l&15)][32*ks + 8*(l>>4) + i], i=0..7 (bf16)
__global__ void prep_weights(const float* __restrict__ qkv_w,
                             const float* __restrict__ proj_w,
                             unsigned char* __restrict__ ws) {
  int g = blockIdx.x;   // 0..511
  int l = threadIdx.x;  // 0..63
  int lr = l & 15, lg = l >> 4;
  const float* src;
  float sc = 1.f;
  if (g < 384) {
    int rt = g >> 3, ks = g & 7;
    src = qkv_w + (size_t)(16 * rt + lr) * 256 + 32 * ks + 8 * lg;
    if (rt < 16) sc = QSCALE * LOG2E;  // fold scale and log2e into q rows
  } else {
    int p = g - 384;
    int rt = p >> 3, ks = p & 7;
    src = proj_w + (size_t)(16 * rt + lr) * 256 + 32 * ks + 8 * lg;
  }
  f32x4 a = *(const f32x4*)(src)*sc;
  f32x4 b = *(const f32x4*)(src + 4) * sc;
  unsigned long long* dst = (unsigned long long*)(ws + (size_t)g * 1024 + l * 16);
  dst[0] = pack4bf(a);
  dst[1] = pack4bf(b);
}

__global__ void prep_aux(const float* __restrict__ mask,
                         const float* __restrict__ bias_table,
                         const float* __restrict__ qkv_b,
                         unsigned char* __restrict__ ws) {
  int bid = blockIdx.x, tid = threadIdx.x;
  if (bid < 64) {  // maskp[w][64][64] * log2e
    float* dst = (float*)(ws + WS_MASKP) + (size_t)bid * 4096;
    for (int it = 0; it < 16; ++it) {
      int idx = it * 256 + tid;
      int m = idx >> 6, j = idx & 63;
      float v;
      if (j >= 49) v = -1e30f;
      else if (m >= 49) v = 0.f;
      else v = mask[((size_t)bid * 49 + m) * 49 + j] * LOG2E;
      dst[idx] = v;
    }
  } else if (bid < 72) {  // bias_hm[h][64][64] * log2e
    int h = bid - 64;
    float* dst = (float*)(ws + WS_BIAS) + (size_t)h * 4096;
    for (int it = 0; it < 16; ++it) {
      int idx = it * 256 + tid;
      int m = idx >> 6, j = idx & 63;
      float v = 0.f;
      if (m < 49 && j < 49) {
        int rm = m / 7, cm = m % 7, rj = j / 7, cj = j % 7;
        int rpi = (rm - rj + 6) * 13 + (cm - cj + 6);
        v = bias_table[rpi * 8 + h] * LOG2E;
      }
      dst[idx] = v;
    }
  } else {  // qkv bias: q part prescaled
    float* dst = (float*)(ws + WS_QB);
    for (int i = tid; i < 768; i += 256)
      dst[i] = qkv_b[i] * (i < 256 ? QSCALE * LOG2E : 1.f);
  }
}

// One block = one window, 4 waves (256 thr); wave wv handles heads 2wv, 2wv+1.
// LDS 52 KiB -> 3 blocks/CU (156K <= 160K).
//  [0,32K)  xs: bf16 x[64][256], byte(r,c) = r*512 + ((2c) ^ ((r&7)<<4));
//           reused as ao[m][256ch] after sync2 (same swizzle on (m&7))
//  per-wave: bufQ = 32768 + wv*5120 (4K: q -> k -> vT stages, reused per head)
//            bufP = bufQ + 4096    (1K: P quarter [16m][32j])
__global__ __launch_bounds__(256, 3)
void winattn_main(const float* __restrict__ x,
                  const unsigned char* __restrict__ ws,
                  const float* __restrict__ proj_b,
                  float* __restrict__ out) {
  __shared__ __align__(16) unsigned char lds[53248];
  const int tid = threadIdx.x;
  const int wv = tid >> 6, ln = tid & 63;
  const int lr = ln & 15, lg = ln >> 4;
  const int b = blockIdx.x;
  const int w = b & 63;
  const float* maskp = (const float*)(ws + WS_MASKP) + (size_t)w * 4096;
  const float* qbs = (const float*)(ws + WS_QB);
  unsigned char* bufQ = lds + 32768 + wv * 5120;
  unsigned char* bufP = bufQ + 4096;

  // ---- Phase 1: stage x -> xs (bf16, swizzled), rows >= 49 zeroed
  {
    const int r = tid >> 2;          // 0..63
    const int c0 = (tid & 3) * 4;    // 0,4,8,12
    const float* xrow = x + ((size_t)b * 49 + r) * 256;
    unsigned char* row = lds + r * 512;
    const int swz = (r & 7) << 4;
#pragma unroll
    for (int u = 0; u < 16; ++u) {
      int c = c0 + 16 * u;
      f32x4 v = {0.f, 0.f, 0.f, 0.f};
      if (r < 49) v = *(const f32x4*)(xrow + c);
      *(unsigned long long*)(row + ((2 * c) ^ swz)) = pack4bf(v);
    }
  }
  __syncthreads();

  unsigned long long aoPk[2][2][4];  // [head01][dt][mq] packed bf16x4

#pragma unroll
  for (int hi = 0; hi < 2; ++hi) {
    const int h = 2 * wv + hi;
    const float* biasp = (const float*)(ws + WS_BIAS) + (size_t)h * 4096;

    // ---- QKV GEMMs for head h (wave-private staging through bufQ)
    bf16x8 qf[4], kf[4];
#pragma unroll
    for (int gp = 0; gp < 3; ++gp) {  // 0=q, 1=k, 2=v
#pragma unroll
      for (int g2 = 0; g2 < 2; ++g2) {
        const int rt = (gp == 0 ? 2 * h : gp == 1 ? 16 + 2 * h : 32 + 2 * h) + g2;
        bf16x8 af[8];
#pragma unroll
        for (int ks = 0; ks < 8; ++ks)
          af[ks] = *(const bf16x8*)(ws + (size_t)(rt * 8 + ks) * 1024 + ln * 16);
        f32x4 b4 = {0.f, 0.f, 0.f, 0.f};
        float vb = 0.f;
        if (gp < 2)
          b4 = *(const f32x4*)(qbs + (gp == 0 ? 0 : 256) + 32 * h + 16 * g2 + 4 * lg);
        else
          vb = qbs[512 + 32 * h + 16 * g2 + lr];
#pragma unroll
        for (int t = 0; t < 4; ++t) {
          const int row = 16 * t + lr;
          const unsigned char* rp = lds + row * 512;
          const int swz = (row & 7) << 4;
          bf16x8 xfr[8];
#pragma unroll
          for (int ks = 0; ks < 8; ++ks)
            xfr[ks] = *(const bf16x8*)(rp + ((64 * ks + 16 * lg) ^ swz));
          f32x4 acc = {0.f, 0.f, 0.f, 0.f};
          if (gp < 2) {
            // D[ch][tok]: col = tok = lr, rows = ch = 16g2+4lg+r2
#pragma unroll
            for (int ks = 0; ks < 8; ++ks)
              acc = __builtin_amdgcn_mfma_f32_16x16x32_bf16(af[ks], xfr[ks], acc, 0, 0, 0);
            acc += b4;
            const int m = 16 * t + lr;
            *(unsigned long long*)(bufQ + m * 64 + ((32 * g2 + 8 * lg) ^ ((lr & 3) << 4))) =
                pack4bf(acc);
          } else {
            // D[tok][d]: col = d = lr+16g2, rows = tok -> vT[d][tok]
#pragma unroll
            for (int ks = 0; ks < 8; ++ks)
              acc = __builtin_amdgcn_mfma_f32_16x16x32_bf16(xfr[ks], af[ks], acc, 0, 0, 0);
            acc += vb;
            const int d = lr + 16 * g2;
            *(unsigned long long*)(bufQ + d * 128 + ((32 * t + 8 * lg) ^ ((d & 7) << 4))) =
                pack4bf(acc);
          }
        }
      }
      if (gp == 0) {
#pragma unroll
        for (int t = 0; t < 4; ++t)
          qf[t] = *(const bf16x8*)(bufQ + (lr + 16 * t) * 64 + ((16 * lg) ^ ((lr & 3) << 4)));
      } else if (gp == 1) {
#pragma unroll
        for (int t = 0; t < 4; ++t)
          kf[t] = *(const bf16x8*)(bufQ + (lr + 16 * t) * 64 + ((16 * lg) ^ ((lr & 3) << 4)));
      }
    }

    // ---- Attention: online over two j-halves; no max-subtract (logits bounded),
    //      normalization deferred to epilogue.
    float sm[4] = {0.f, 0.f, 0.f, 0.f};
    f32x4 oacc[2][4];
#pragma unroll
    for (int dt = 0; dt < 2; ++dt)
#pragma unroll
      for (int mq = 0; mq < 4; ++mq) oacc[dt][mq] = {0.f, 0.f, 0.f, 0.f};

#pragma unroll
    for (int jh = 0; jh < 2; ++jh) {
      f32x4 s2[2][4];
#pragma unroll
      for (int jt2 = 0; jt2 < 2; ++jt2) {
        const int jt = 2 * jh + jt2;
#pragma unroll
        for (int mtc = 0; mtc < 4; ++mtc) {
          const int m = lr + 16 * mtc;
          f32x4 mk = *(const f32x4*)(maskp + m * 64 + 16 * jt + 4 * lg);
          f32x4 sv = __builtin_amdgcn_mfma_f32_16x16x32_bf16(kf[jt], qf[mtc], mk, 0, 0, 0);
          sv += *(const f32x4*)(biasp + m * 64 + 16 * jt + 4 * lg);
#pragma unroll
          for (int r2 = 0; r2 < 4; ++r2) {
            float e = __builtin_amdgcn_exp2f(sv[r2]);
            s2[jt2][mtc][r2] = e;
            sm[mtc] += e;
          }
        }
      }
      bf16x8 vf[2];
#pragma unroll
      for (int dt = 0; dt < 2; ++dt) {
        const int d = lr + 16 * dt;
        vf[dt] = *(const bf16x8*)(bufQ + d * 128 + ((64 * jh + 16 * lg) ^ ((d & 7) << 4)));
      }
#pragma unroll
      for (int mq = 0; mq < 4; ++mq) {
#pragma unroll
        for (int jt2 = 0; jt2 < 2; ++jt2)
          *(unsigned long long*)(bufP + lr * 64 + ((32 * jt2 + 8 * lg) ^ ((lr & 3) << 4))) =
              pack4bf(s2[jt2][mq]);
        bf16x8 pf = *(const bf16x8*)(bufP + lr * 64 + ((16 * lg) ^ ((lr & 3) << 4)));
#pragma unroll
        for (int dt = 0; dt < 2; ++dt)
          oacc[dt][mq] = __builtin_amdgcn_mfma_f32_16x16x32_bf16(vf[dt], pf, oacc[dt][mq], 0, 0, 0);
      }
    }
#pragma unroll
    for (int mq = 0; mq < 4; ++mq) {
      float s = sm[mq];
      s += __shfl_xor(s, 16);
      s += __shfl_xor(s, 32);
      float inv = 1.f / s;
#pragma unroll
      for (int dt = 0; dt < 2; ++dt) aoPk[hi][dt][mq] = pack4bf(oacc[dt][mq] * inv);
    }
  }
  __syncthreads();  // all waves done reading xs -> safe to overwrite with ao

  // ao[m][256] into xs region: head h owns bytes [64h, 64h+64) per row
#pragma unroll
  for (int hi = 0; hi < 2; ++hi) {
    const int h = 2 * wv + hi;
#pragma unroll
    for (int dt = 0; dt < 2; ++dt)
#pragma unroll
      for (int mq = 0; mq < 4; ++mq) {
        const int m = lr + 16 * mq;
        *(unsigned long long*)(lds + m * 512 +
                               ((64 * h + 32 * dt + 8 * lg) ^ ((m & 7) << 4))) =
            aoPk[hi][dt][mq];
      }
  }
  __syncthreads();

  // ---- Phase D: proj^T[o][m] = sum_c Wp[o][c] * ao[m][c]
  const unsigned char* wsP = ws + WS_PROJ;
#pragma unroll
  for (int tt = 0; tt < 4; ++tt) {
    const int m = lr + 16 * tt;
    bf16x8 aof[8];
#pragma unroll
    for (int ks = 0; ks < 8; ++ks)
      aof[ks] = *(const bf16x8*)(lds + m * 512 + ((64 * ks + 16 * lg) ^ ((m & 7) << 4)));
#pragma unroll
    for (int i = 0; i < 4; ++i) {
      const int mt = 4 * wv + i;
      bf16x8 af[8];
#pragma unroll
      for (int ks = 0; ks < 8; ++ks)
        af[ks] = *(const bf16x8*)(wsP + (size_t)(mt * 8 + ks) * 1024 + ln * 16);
      f32x4 acc = {0.f, 0.f, 0.f, 0.f};
#pragma unroll
      for (int ks = 0; ks < 8; ++ks)
        acc = __builtin_amdgcn_mfma_f32_16x16x32_bf16(af[ks], aof[ks], acc, 0, 0, 0);
      if (m < 49) {
        f32x4 pb = *(const f32x4*)(proj_b + 16 * mt + 4 * lg);
        acc += pb;
        *(f32x4*)(out + ((size_t)b * 49 + m) * 256 + 16 * mt + 4 * lg) = acc;
      }
    }
  }
}

extern "C" void kernel_launch(void* const* d_in, const int* in_sizes, int n_in,
                              void* d_out, int out_size, void* d_ws, size_t ws_size,
                              hipStream_t stream) {
  const float* x = (const float*)d_in[0];
  const float* mask = (const float*)d_in[1];
  const float* qkv_w = (const float*)d_in[2];
  const float* qkv_b = (const float*)d_in[3];
  const float* proj_w = (const float*)d_in[4];
  const float* proj_b = (const float*)d_in[5];
  const float* bias_table = (const float*)d_in[6];
  unsigned char* ws = (unsigned char*)d_ws;
  float* out = (float*)d_out;

  prep_weights<<<512, 64, 0, stream>>>(qkv_w, proj_w, ws);
  prep_aux<<<73, 256, 0, stream>>>(mask, bias_table, qkv_b, ws);
  winattn_main<<<4096, 256, 0, stream>>>(x, ws, proj_b, out);
}

// Round 5
// 401.292 us; speedup vs baseline: 1.4610x; 1.4610x over previous
//
#include <hip/hip_runtime.h>

typedef __attribute__((ext_vector_type(8))) short bf16x8;
typedef __attribute__((ext_vector_type(4))) float f32x4;

#define WS_QKV   0          // 384 KiB: qkv frags (48 rt * 8 ks * 1024B), q-rows prescaled
#define WS_PROJ  393216     // 128 KiB: proj frags (16 rt * 8 ks * 1024B)
#define WS_MASKP 524288     // 1 MiB: maskp[64][64][64] f32 * log2e (j>=49 -> -1e30)
#define WS_BIAS  1572864    // 128 KiB: bias_hm[8][64][64] f32 * log2e
#define WS_QB    1703936    // 3 KiB: qkvb_s[768] (q part prescaled by scale*log2e)

#define QSCALE 0.17677669529663687f   // 1/sqrt(32)
#define LOG2E  1.4426950408889634f

__device__ __forceinline__ unsigned short f2bf(float f) {
  unsigned u = __builtin_bit_cast(unsigned, f);
  u += 0x7FFFu + ((u >> 16) & 1u);
  return (unsigned short)(u >> 16);
}

__device__ __forceinline__ unsigned long long pack4bf(f32x4 v) {
  unsigned long long r0 = f2bf(v[0]);
  unsigned long long r1 = f2bf(v[1]);
  unsigned long long r2 = f2bf(v[2]);
  unsigned long long r3 = f2bf(v[3]);
  return r0 | (r1 << 16) | (r2 << 32) | (r3 << 48);
}

// frag(rt,ks): lane l holds W[16*rt + (l&15)][32*ks + 8*(l>>4) + i], i=0..7 (bf16)
__global__ void prep_weights(const float* __restrict__ qkv_w,
                             const float* __restrict__ proj_w,
                             unsigned char* __restrict__ ws) {
  int g = blockIdx.x;   // 0..511
  int l = threadIdx.x;  // 0..63
  int lr = l & 15, lg = l >> 4;
  const float* src;
  float sc = 1.f;
  if (g < 384) {
    int rt = g >> 3, ks = g & 7;
    src = qkv_w + (size_t)(16 * rt + lr) * 256 + 32 * ks + 8 * lg;
    if (rt < 16) sc = QSCALE * LOG2E;  // fold scale and log2e into q rows
  } else {
    int p = g - 384;
    int rt = p >> 3, ks = p & 7;
    src = proj_w + (size_t)(16 * rt + lr) * 256 + 32 * ks + 8 * lg;
  }
  f32x4 a = *(const f32x4*)(src)*sc;
  f32x4 b = *(const f32x4*)(src + 4) * sc;
  unsigned long long* dst = (unsigned long long*)(ws + (size_t)g * 1024 + l * 16);
  dst[0] = pack4bf(a);
  dst[1] = pack4bf(b);
}

__global__ void prep_aux(const float* __restrict__ mask,
                         const float* __restrict__ bias_table,
                         const float* __restrict__ qkv_b,
                         unsigned char* __restrict__ ws) {
  int bid = blockIdx.x, tid = threadIdx.x;
  if (bid < 64) {  // maskp[w][64][64] * log2e
    float* dst = (float*)(ws + WS_MASKP) + (size_t)bid * 4096;
    for (int it = 0; it < 16; ++it) {
      int idx = it * 256 + tid;
      int m = idx >> 6, j = idx & 63;
      float v;
      if (j >= 49) v = -1e30f;
      else if (m >= 49) v = 0.f;
      else v = mask[((size_t)bid * 49 + m) * 49 + j] * LOG2E;
      dst[idx] = v;
    }
  } else if (bid < 72) {  // bias_hm[h][64][64] * log2e
    int h = bid - 64;
    float* dst = (float*)(ws + WS_BIAS) + (size_t)h * 4096;
    for (int it = 0; it < 16; ++it) {
      int idx = it * 256 + tid;
      int m = idx >> 6, j = idx & 63;
      float v = 0.f;
      if (m < 49 && j < 49) {
        int rm = m / 7, cm = m % 7, rj = j / 7, cj = j % 7;
        int rpi = (rm - rj + 6) * 13 + (cm - cj + 6);
        v = bias_table[rpi * 8 + h] * LOG2E;
      }
      dst[idx] = v;
    }
  } else {  // qkv bias: q part prescaled
    float* dst = (float*)(ws + WS_QB);
    for (int i = tid; i < 768; i += 256)
      dst[i] = qkv_b[i] * (i < 256 ? QSCALE * LOG2E : 1.f);
  }
}

// One block = one window; wave wv = head wv. 8 waves. LDS 77 KiB.
//  [0,32K)  xs: bf16 x[64][256], byte(r,c) = r*512 + ((2c) ^ ((r&7)<<4));
//           reused as ao[m][256ch] after sync2 (same swizzle on (m&7))
//  per-wave bufA = 32768 + wv*5760, 4608 B (stages q -> k -> vT):
//    q/k: [m][32d] stride 72 B (conflict-free: 18 banks/row, gcd(18,32)=2)
//    vT:  [d][64tok] stride 128 B, byte = d*128 + ((2*tok) ^ ((d&7)<<4))
//  per-wave bufP = bufA + 4608, 1152 B: [16 m][32 j] stride 72 B
__global__ __launch_bounds__(512, 2)
void winattn_main(const float* __restrict__ x,
                  const unsigned char* __restrict__ ws,
                  const float* __restrict__ proj_b,
                  float* __restrict__ out) {
  __shared__ __align__(16) unsigned char lds[78848];
  const int tid = threadIdx.x;
  const int wv = tid >> 6, ln = tid & 63;
  const int lr = ln & 15, lg = ln >> 4;
  const int b = blockIdx.x;
  const int w = b & 63, h = wv;
  const float* maskp = (const float*)(ws + WS_MASKP) + (size_t)w * 4096;
  const float* biasp = (const float*)(ws + WS_BIAS) + (size_t)h * 4096;
  const float* qbs = (const float*)(ws + WS_QB);
  unsigned char* bufA = lds + 32768 + wv * 5760;
  unsigned char* bufP = bufA + 4608;

  // ---- Phase 1: stage x -> xs (bf16, swizzled), rows >= 49 zeroed
  {
    const int r = tid >> 3;
    const int c0 = (tid & 7) * 4;
    const float* xrow = x + ((size_t)b * 49 + r) * 256;
    unsigned char* row = lds + r * 512;
    const int swz = (r & 7) << 4;
#pragma unroll
    for (int u = 0; u < 8; ++u) {
      int c = c0 + 32 * u;
      f32x4 v = {0.f, 0.f, 0.f, 0.f};
      if (r < 49) v = *(const f32x4*)(xrow + c);
      *(unsigned long long*)(row + ((2 * c) ^ swz)) = pack4bf(v);
    }
  }
  __syncthreads();

  // ---- Phase B: QKV GEMMs; each pp pairs the two 16-ch groups so one xfr
  //      load feeds two MFMA chains (halves LDS reads, doubles acc ILP).
  bf16x8 qf[4], kf[4];
#pragma unroll
  for (int pp = 0; pp < 3; ++pp) {  // 0=q, 1=k, 2=v
    const int rtb = (pp == 0 ? 0 : (pp == 1 ? 16 : 32)) + 2 * h;
    bf16x8 af0[8], af1[8];
#pragma unroll
    for (int ks = 0; ks < 8; ++ks) {
      af0[ks] = *(const bf16x8*)(ws + (size_t)(rtb * 8 + ks) * 1024 + ln * 16);
      af1[ks] = *(const bf16x8*)(ws + (size_t)((rtb + 1) * 8 + ks) * 1024 + ln * 16);
    }
    f32x4 c0, c1;
    if (pp < 2) {
      c0 = *(const f32x4*)(qbs + pp * 256 + 32 * h + 4 * lg);
      c1 = *(const f32x4*)(qbs + pp * 256 + 32 * h + 16 + 4 * lg);
    } else {
      float vb0 = qbs[512 + 32 * h + lr];
      float vb1 = qbs[512 + 32 * h + 16 + lr];
      c0 = {vb0, vb0, vb0, vb0};
      c1 = {vb1, vb1, vb1, vb1};
    }
#pragma unroll
    for (int t = 0; t < 4; ++t) {
      const int row = 16 * t + lr;
      const unsigned char* rp = lds + row * 512;
      const int swz = (row & 7) << 4;
      bf16x8 xfr[8];
#pragma unroll
      for (int ks = 0; ks < 8; ++ks)
        xfr[ks] = *(const bf16x8*)(rp + ((64 * ks + 16 * lg) ^ swz));
      f32x4 a0 = c0, a1 = c1;
      if (pp < 2) {
        // D[ch][tok]: col = tok = lr, rows = ch
#pragma unroll
        for (int ks = 0; ks < 8; ++ks) {
          a0 = __builtin_amdgcn_mfma_f32_16x16x32_bf16(af0[ks], xfr[ks], a0, 0, 0, 0);
          a1 = __builtin_amdgcn_mfma_f32_16x16x32_bf16(af1[ks], xfr[ks], a1, 0, 0, 0);
        }
        *(unsigned long long*)(bufA + row * 72 + 8 * lg) = pack4bf(a0);
        *(unsigned long long*)(bufA + row * 72 + 32 + 8 * lg) = pack4bf(a1);
      } else {
        // D[tok][d]: col = d, rows = tok -> vT[d][tok]
#pragma unroll
        for (int ks = 0; ks < 8; ++ks) {
          a0 = __builtin_amdgcn_mfma_f32_16x16x32_bf16(xfr[ks], af0[ks], a0, 0, 0, 0);
          a1 = __builtin_amdgcn_mfma_f32_16x16x32_bf16(xfr[ks], af1[ks], a1, 0, 0, 0);
        }
        const int tb = 32 * t + 8 * lg;
        *(unsigned long long*)(bufA + lr * 128 + (tb ^ ((lr & 7) << 4))) = pack4bf(a0);
        *(unsigned long long*)(bufA + (16 + lr) * 128 + (tb ^ ((lr & 7) << 4))) = pack4bf(a1);
      }
    }
    if (pp == 0) {
#pragma unroll
      for (int t = 0; t < 4; ++t)
        qf[t] = *(const bf16x8*)(bufA + (lr + 16 * t) * 72 + 16 * lg);
    } else if (pp == 1) {
#pragma unroll
      for (int t = 0; t < 4; ++t)
        kf[t] = *(const bf16x8*)(bufA + (lr + 16 * t) * 72 + 16 * lg);
    }
  }

  // ---- Phase C: S^T = K Q^T with C-init = mask+bias; exp2 softmax (no max-
  //      subtract: logits bounded, masked cols -> -1e30 -> exp2 -> 0)
  f32x4 s[4][4];
#pragma unroll
  for (int mtc = 0; mtc < 4; ++mtc) {
    const int m = lr + 16 * mtc;
    const float* mrow = maskp + m * 64;
    const float* brow = biasp + m * 64;
#pragma unroll
    for (int jt = 0; jt < 4; ++jt) {
      f32x4 mk = *(const f32x4*)(mrow + 16 * jt + 4 * lg) +
                 *(const f32x4*)(brow + 16 * jt + 4 * lg);
      s[jt][mtc] = __builtin_amdgcn_mfma_f32_16x16x32_bf16(kf[jt], qf[mtc], mk, 0, 0, 0);
    }
  }
  float inv[4];
#pragma unroll
  for (int mtc = 0; mtc < 4; ++mtc) {
    float sm = 0.f;
#pragma unroll
    for (int jt = 0; jt < 4; ++jt)
#pragma unroll
      for (int r2 = 0; r2 < 4; ++r2) {
        float e = __builtin_amdgcn_exp2f(s[jt][mtc][r2]);
        s[jt][mtc][r2] = e;
        sm += e;
      }
    sm += __shfl_xor(sm, 16);
    sm += __shfl_xor(sm, 32);
    inv[mtc] = 1.f / sm;  // normalization deferred to PV epilogue
  }

  // ---- PV through wave-private bufP (16 rows, stride 72)
  f32x4 oacc[2][4];
#pragma unroll
  for (int dt = 0; dt < 2; ++dt)
#pragma unroll
    for (int mq = 0; mq < 4; ++mq) oacc[dt][mq] = {0.f, 0.f, 0.f, 0.f};
#pragma unroll
  for (int jh = 0; jh < 2; ++jh) {
    bf16x8 vf[2];
#pragma unroll
    for (int dt = 0; dt < 2; ++dt) {
      const int d = lr + 16 * dt;
      vf[dt] = *(const bf16x8*)(bufA + d * 128 + ((64 * jh + 16 * lg) ^ ((d & 7) << 4)));
    }
#pragma unroll
    for (int mq = 0; mq < 4; ++mq) {
#pragma unroll
      for (int jt2 = 0; jt2 < 2; ++jt2)
        *(unsigned long long*)(bufP + lr * 72 + 32 * jt2 + 8 * lg) =
            pack4bf(s[2 * jh + jt2][mq]);
      bf16x8 pf = *(const bf16x8*)(bufP + lr * 72 + 16 * lg);
#pragma unroll
      for (int dt = 0; dt < 2; ++dt)
        oacc[dt][mq] = __builtin_amdgcn_mfma_f32_16x16x32_bf16(vf[dt], pf, oacc[dt][mq], 0, 0, 0);
    }
  }

  __syncthreads();  // all waves done reading xs -> safe to overwrite with ao

  // ao[m][256] into xs region: head h owns bytes [64h, 64h+64) per row
#pragma unroll
  for (int dt = 0; dt < 2; ++dt)
#pragma unroll
    for (int mq = 0; mq < 4; ++mq) {
      const int m = lr + 16 * mq;
      *(unsigned long long*)(lds + m * 512 +
                             ((64 * h + 32 * dt + 8 * lg) ^ ((m & 7) << 4))) =
          pack4bf(oacc[dt][mq] * inv[mq]);
    }
  __syncthreads();

  // ---- Phase D: proj^T[o][m] = sum_c Wp[o][c] * ao[m][c]
  const unsigned char* wsP = ws + WS_PROJ;
#pragma unroll
  for (int tt = 0; tt < 4; ++tt) {
    const int m = lr + 16 * tt;
    bf16x8 aof[8];
#pragma unroll
    for (int ks = 0; ks < 8; ++ks)
      aof[ks] = *(const bf16x8*)(lds + m * 512 + ((64 * ks + 16 * lg) ^ ((m & 7) << 4)));
#pragma unroll
    for (int i = 0; i < 2; ++i) {
      const int mt = 2 * wv + i;
      bf16x8 af[8];
#pragma unroll
      for (int ks = 0; ks < 8; ++ks)
        af[ks] = *(const bf16x8*)(wsP + (size_t)(mt * 8 + ks) * 1024 + ln * 16);
      f32x4 acc = {0.f, 0.f, 0.f, 0.f};
#pragma unroll
      for (int ks = 0; ks < 8; ++ks)
        acc = __builtin_amdgcn_mfma_f32_16x16x32_bf16(af[ks], aof[ks], acc, 0, 0, 0);
      if (m < 49) {
        f32x4 pb = *(const f32x4*)(proj_b + 16 * mt + 4 * lg);
        acc += pb;
        *(f32x4*)(out + ((size_t)b * 49 + m) * 256 + 16 * mt + 4 * lg) = acc;
      }
    }
  }
}

extern "C" void kernel_launch(void* const* d_in, const int* in_sizes, int n_in,
                              void* d_out, int out_size, void* d_ws, size_t ws_size,
                              hipStream_t stream) {
  const float* x = (const float*)d_in[0];
  const float* mask = (const float*)d_in[1];
  const float* qkv_w = (const float*)d_in[2];
  const float* qkv_b = (const float*)d_in[3];
  const float* proj_w = (const float*)d_in[4];
  const float* proj_b = (const float*)d_in[5];
  const float* bias_table = (const float*)d_in[6];
  unsigned char* ws = (unsigned char*)d_ws;
  float* out = (float*)d_out;

  prep_weights<<<512, 64, 0, stream>>>(qkv_w, proj_w, ws);
  prep_aux<<<73, 256, 0, stream>>>(mask, bias_table, qkv_b, ws);
  winattn_main<<<4096, 512, 0, stream>>>(x, ws, proj_b, out);
}